// Round 4
// baseline (46886.804 us; speedup 1.0000x reference)
//
#include <hip/hip_runtime.h>
#include <math.h>

#define NB   8          // rows per block
#define TT   400
#define HH   128
#define CC   96
#define DD   4096
#define GJ   512
#define THRV (1.0f - 1e-5f)

__device__ __forceinline__ float sigm(float v) { return 1.0f / (1.0f + expf(-v)); }

__global__ __launch_bounds__(512, 2)
void gru_title(const float* __restrict__ img,
               const float* __restrict__ l1w,
               const float* __restrict__ l1b,
               const float* __restrict__ wih,
               const float* __restrict__ whh,
               const float* __restrict__ bih,
               const float* __restrict__ bhh,
               const float* __restrict__ l2w,
               const float* __restrict__ l2b,
               float* __restrict__ out,
               float* __restrict__ lens)
{
    __shared__ alignas(16) float xs[NB][HH];    // h_t
    __shared__ alignas(16) float xl[NB][HH];    // leaky(h_t)
    __shared__ alignas(16) float gs[NB][GJ];    // gate pre-activations
    __shared__ alignas(16) float chs[NB][CC];   // last computed chars per row
    __shared__ alignas(16) float l2t[HH/4][CC][4]; // l2w transposed, float4 per k4 (48 KB)
    __shared__ int sh_changed[NB];
    __shared__ int sh_ts[NB];                   // per-row retirement step

    const int tid = threadIdx.x;
    const int b0  = blockIdx.x * NB;

    // ---- combined gate weights, register/AGPR-resident (verbatim from R3) ----
    float wreg[HH];
    float bj;
    if (tid < 256) {
        const float4* p0 = (const float4*)(wih + (size_t)tid * HH);
        const float4* p1 = (const float4*)(whh + (size_t)tid * HH);
        #pragma unroll
        for (int k = 0; k < HH/4; ++k) {
            float4 a = p0[k], b = p1[k];
            wreg[4*k+0] = a.x + b.x; wreg[4*k+1] = a.y + b.y;
            wreg[4*k+2] = a.z + b.z; wreg[4*k+3] = a.w + b.w;
        }
        bj = bih[tid] + bhh[tid];
    } else if (tid < 384) {
        const float4* p0 = (const float4*)(wih + (size_t)tid * HH);
        #pragma unroll
        for (int k = 0; k < HH/4; ++k) {
            float4 a = p0[k];
            wreg[4*k+0] = a.x; wreg[4*k+1] = a.y; wreg[4*k+2] = a.z; wreg[4*k+3] = a.w;
        }
        bj = bih[tid];
    } else {
        const float4* p0 = (const float4*)(whh + (size_t)(tid - 128) * HH);
        #pragma unroll
        for (int k = 0; k < HH/4; ++k) {
            float4 a = p0[k];
            wreg[4*k+0] = a.x; wreg[4*k+1] = a.y; wreg[4*k+2] = a.z; wreg[4*k+3] = a.w;
        }
        bj = bhh[tid - 128];
    }

    // ---- chars-phase constants: thread (c3, g3) handles rows 2*g3, 2*g3+1 ----
    const int   c3    = tid % CC;          // 0..95
    const int   g3    = tid / CC;          // 0..5 (only 0..3 used)
    const float cbias = l2b[c3];

    // ---- stage l2w into LDS transposed: l2t[k4][c] = l2w[c][4k4..4k4+4) ----
    for (int idx = tid; idx < CC * HH; idx += 512) {
        int c = idx / HH, k = idx % HH;
        l2t[k >> 2][c][k & 3] = l2w[idx];
    }
    if (tid < NB) { sh_changed[tid] = 0; sh_ts[tid] = TT; }

    // ---- prologue: x0 = leaky(img @ l1w.T + l1b), 2 rows per thread ----
    {
        const int c  = tid & 127;
        const int mh = tid >> 7;            // 0..3
        const int r0 = 2*mh, r1 = r0 + 1;
        const float4* xp0 = (const float4*)(img + (size_t)(b0 + r0) * DD);
        const float4* xp1 = (const float4*)(img + (size_t)(b0 + r1) * DD);
        const float4* wp  = (const float4*)(l1w + (size_t)c * DD);
        float a0 = 0.f, b0v = 0.f, a1 = 0.f, b1v = 0.f;
        #pragma unroll 4
        for (int k = 0; k < DD/4; k += 2) {
            float4 w0 = wp[k],  w1 = wp[k+1];
            float4 u0 = xp0[k], u1 = xp0[k+1];
            float4 v0 = xp1[k], v1 = xp1[k+1];
            a0  += w0.x*u0.x + w0.y*u0.y + w0.z*u0.z + w0.w*u0.w;
            b0v += w1.x*u1.x + w1.y*u1.y + w1.z*u1.z + w1.w*u1.w;
            a1  += w0.x*v0.x + w0.y*v0.y + w0.z*v0.z + w0.w*v0.w;
            b1v += w1.x*v1.x + w1.y*v1.y + w1.z*v1.z + w1.w*v1.w;
        }
        float h0 = a0 + b0v + l1b[c];
        float h1 = a1 + b1v + l1b[c];
        xs[r0][c] = (h0 >= 0.f) ? h0 : 0.01f*h0;
        xs[r1][c] = (h1 >= 0.f) ? h1 : 0.01f*h1;
    }
    __syncthreads();

    const int wav  = tid >> 6;
    const int lane = tid & 63;
    int  len   = TT;
    bool found = false;
    int  act   = 0xFF;          // active-row mask, block-uniform

    for (int t = 0; t < TT; ++t) {
        if (tid < NB) sh_changed[tid] = 0;   // vs phase-2 writes: barrier A; vs
                                             // prev retirement read: barrier C(t-1)

        // ---------- gates GEMM (R3 arithmetic, per-row guarded) ----------
        if (t == 0) {
            float acc[NB];
            #pragma unroll
            for (int m = 0; m < NB; ++m) acc[m] = bj;
            if (tid < 384) {
                const float4* wp = (const float4*)(wih + (size_t)tid * HH);
                #pragma unroll
                for (int k = 0; k < HH/4; ++k) {
                    float4 w = wp[k];
                    #pragma unroll
                    for (int m = 0; m < NB; ++m) {
                        float4 x = *(const float4*)&xs[m][4*k];
                        acc[m] += w.x*x.x + w.y*x.y + w.z*x.z + w.w*x.w;
                    }
                }
            }
            #pragma unroll
            for (int m = 0; m < NB; ++m) gs[m][tid] = acc[m];
        } else {
            #pragma unroll
            for (int m = 0; m < NB; ++m) {
                if (act & (1 << m)) {
                    float s0 = bj, s1 = 0.f;
                    #pragma unroll
                    for (int k = 0; k < HH/8; ++k) {
                        float4 x0 = *(const float4*)&xs[m][8*k];
                        float4 x1 = *(const float4*)&xs[m][8*k+4];
                        s0 += x0.x*wreg[8*k+0] + x0.y*wreg[8*k+1] + x0.z*wreg[8*k+2] + x0.w*wreg[8*k+3];
                        s1 += x1.x*wreg[8*k+4] + x1.y*wreg[8*k+5] + x1.z*wreg[8*k+6] + x1.w*wreg[8*k+7];
                    }
                    gs[m][tid] = s0 + s1;
                }
            }
        }
        __syncthreads();   // A

        // ---------- gate nonlinearity + state update + change detect ----------
        {
            const int i  = tid & 127;
            const int mh = tid >> 7;
            #pragma unroll
            for (int g = 0; g < 2; ++g) {
                const int m = mh + 4*g;
                if (act & (1 << m)) {
                    float r  = sigm(gs[m][i]);
                    float z  = sigm(gs[m][HH + i]);
                    float n  = tanhf(gs[m][2*HH + i] + r * gs[m][3*HH + i]);
                    float hp = (t == 0) ? 0.f : xs[m][i];
                    float h  = (1.f - z) * n + z * hp;
                    if (__float_as_uint(h) != __float_as_uint(hp)) sh_changed[m] = 1;
                    xs[m][i] = h;
                    xl[m][i] = (h >= 0.f) ? h : 0.01f * h;
                }
            }
        }
        __syncthreads();   // B

        // ---------- per-row retirement (uniform across block) ----------
        if (t > 0) {
            int newact = act;
            #pragma unroll
            for (int m = 0; m < NB; ++m)
                if ((act & (1 << m)) && sh_changed[m] == 0) newact &= ~(1 << m);
            if (newact != act) {
                if (tid < NB && ((act & ~newact) >> tid) & 1) sh_ts[tid] = t;
                act = newact;
            }
            act = __builtin_amdgcn_readfirstlane(act);
            if (act == 0) break;
        }

        // ---------- chars from LDS-resident l2t: 384 threads, 2 rows each ----------
        if (tid < 384) {
            const int m0 = 2 * g3, m1 = m0 + 1;
            const bool a0v = (act >> m0) & 1, a1v = (act >> m1) & 1;
            if (a0v | a1v) {
                float a0 = cbias, a1 = cbias;
                #pragma unroll
                for (int k4 = 0; k4 < HH/4; ++k4) {
                    float4 w  = *(const float4*)&l2t[k4][c3][0];
                    float4 x0 = *(const float4*)&xl[m0][4*k4];
                    float4 x1 = *(const float4*)&xl[m1][4*k4];
                    a0 += w.x*x0.x + w.y*x0.y + w.z*x0.z + w.w*x0.w;
                    a1 += w.x*x1.x + w.y*x1.y + w.z*x1.z + w.w*x1.w;
                }
                if (a0v) chs[m0][c3] = a0;
                if (a1v) chs[m1][c3] = a1;
            }
        }
        __syncthreads();   // C

        // ---------- max / divide / threshold / scatter / len (active rows) ----------
        if (act & (1 << wav)) {
            float v0 = chs[wav][lane];
            float v1 = (lane < 32) ? chs[wav][64 + lane] : -INFINITY;
            float mx = fmaxf(v0, v1);
            #pragma unroll
            for (int s = 32; s > 0; s >>= 1) mx = fmaxf(mx, __shfl_xor(mx, s, 64));
            float q0 = v0 / mx;
            size_t base = ((size_t)(b0 + wav) * TT + t) * CC;
            if (q0 > THRV) out[base + lane] = q0;
            if (lane < 32) {
                float q1 = v1 / mx;
                if (q1 > THRV) out[base + 64 + lane] = q1;
            }
            float q52 = __shfl(q0, 52, 64);
            if (!found && q52 == 1.0f) { found = true; len = t + 1; }
        }
        // no trailing barrier: barriers A,B of next iter separate phase-4 chs reads
        // from the next phase-3 chs writes.
    }

    __syncthreads();   // make final sh_ts / chs writes visible

    // ---- epilogue: replicate frozen chars for t in [ts, TT) per retired row ----
    {
        int ts = sh_ts[wav];
        if (ts < TT) {
            float v0 = chs[wav][lane];
            float v1 = (lane < 32) ? chs[wav][64 + lane] : -INFINITY;
            float mx = fmaxf(v0, v1);
            #pragma unroll
            for (int s = 32; s > 0; s >>= 1) mx = fmaxf(mx, __shfl_xor(mx, s, 64));
            size_t rowbase = (size_t)(b0 + wav) * TT * CC;
            float q0 = v0 / mx;
            if (q0 > THRV)
                for (int t = ts; t < TT; ++t) out[rowbase + (size_t)t * CC + lane] = q0;
            if (lane < 32) {
                float q1 = v1 / mx;
                if (q1 > THRV)
                    for (int t = ts; t < TT; ++t) out[rowbase + (size_t)t * CC + 64 + lane] = q1;
            }
            // lens: chars for t >= ts-1 are identical, so any char-52 hit was
            // already recorded while the row was active. len is final.
        }
    }

    if (lane == 0) lens[b0 + wav] = (float)len;
}

extern "C" void kernel_launch(void* const* d_in, const int* in_sizes, int n_in,
                              void* d_out, int out_size, void* d_ws, size_t ws_size,
                              hipStream_t stream)
{
    const float* img = (const float*)d_in[0];
    const float* l1w = (const float*)d_in[1];
    const float* l1b = (const float*)d_in[2];
    const float* wih = (const float*)d_in[3];
    const float* whh = (const float*)d_in[4];
    const float* bih = (const float*)d_in[5];
    const float* bhh = (const float*)d_in[6];
    const float* l2w = (const float*)d_in[7];
    const float* l2b = (const float*)d_in[8];

    float* out  = (float*)d_out;
    float* lens = out + (size_t)2048 * TT * CC;

    // titles is ~99% zeros: clear everything, kernel scatters only survivors.
    hipMemsetAsync(d_out, 0, (size_t)out_size * sizeof(float), stream);

    gru_title<<<dim3(2048 / NB), dim3(512), 0, stream>>>(
        img, l1w, l1b, wih, whh, bih, bhh, l2w, l2b, out, lens);
}

// Round 5
// 5792.935 us; speedup vs baseline: 8.0938x; 8.0938x over previous
//
#include <hip/hip_runtime.h>
#include <math.h>

#define NB   8          // rows per block
#define TT   400
#define HH   128
#define CC   96
#define DD   4096
#define GJ   512
#define THRV (1.0f - 1e-5f)

__device__ __forceinline__ float sigm(float v) { return 1.0f / (1.0f + expf(-v)); }

__global__ __launch_bounds__(512, 2)
void gru_title(const float* __restrict__ img,
               const float* __restrict__ l1w,
               const float* __restrict__ l1b,
               const float* __restrict__ wih,
               const float* __restrict__ whh,
               const float* __restrict__ bih,
               const float* __restrict__ bhh,
               const float* __restrict__ l2w,
               const float* __restrict__ l2b,
               float* __restrict__ out,
               float* __restrict__ lens)
{
    __shared__ alignas(16) float xs[NB][HH];       // h_t
    __shared__ alignas(16) float xl[NB][HH];       // leaky(h_t)
    __shared__ alignas(16) float gs[NB][GJ];       // gate pre-activations
    __shared__ alignas(16) float chs[NB][CC];      // chars
    __shared__ alignas(16) float l2t[HH/4][CC][4]; // l2w transposed (48 KB)
    __shared__ int sh_stable;

    const int tid = threadIdx.x;
    const int b0  = blockIdx.x * NB;

    // ---- combined gate weights, register/AGPR-resident (verbatim R3) ----
    float wreg[HH];
    float bj;
    if (tid < 256) {
        const float4* p0 = (const float4*)(wih + (size_t)tid * HH);
        const float4* p1 = (const float4*)(whh + (size_t)tid * HH);
        #pragma unroll
        for (int k = 0; k < HH/4; ++k) {
            float4 a = p0[k], b = p1[k];
            wreg[4*k+0] = a.x + b.x; wreg[4*k+1] = a.y + b.y;
            wreg[4*k+2] = a.z + b.z; wreg[4*k+3] = a.w + b.w;
        }
        bj = bih[tid] + bhh[tid];
    } else if (tid < 384) {
        const float4* p0 = (const float4*)(wih + (size_t)tid * HH);
        #pragma unroll
        for (int k = 0; k < HH/4; ++k) {
            float4 a = p0[k];
            wreg[4*k+0] = a.x; wreg[4*k+1] = a.y; wreg[4*k+2] = a.z; wreg[4*k+3] = a.w;
        }
        bj = bih[tid];
    } else {
        const float4* p0 = (const float4*)(whh + (size_t)(tid - 128) * HH);
        #pragma unroll
        for (int k = 0; k < HH/4; ++k) {
            float4 a = p0[k];
            wreg[4*k+0] = a.x; wreg[4*k+1] = a.y; wreg[4*k+2] = a.z; wreg[4*k+3] = a.w;
        }
        bj = bhh[tid - 128];
    }

    // ---- chars-phase constants: thread (c3, g3) handles rows 2*g3, 2*g3+1 ----
    const int   c3    = tid % CC;          // 0..95
    const int   g3    = tid / CC;          // 0..5 (only 0..3 work)
    const float cbias = l2b[c3];

    // ---- stage l2w into LDS transposed: l2t[k>>2][c][k&3] = l2w[c][k] ----
    for (int idx = tid; idx < CC * HH; idx += 512) {
        int c = idx / HH, k = idx % HH;
        l2t[k >> 2][c][k & 3] = l2w[idx];
    }

    // ---- prologue: x0 = leaky(img @ l1w.T + l1b), 2 rows per thread ----
    {
        const int c  = tid & 127;
        const int mh = tid >> 7;            // 0..3
        const int r0 = 2*mh, r1 = r0 + 1;
        const float4* xp0 = (const float4*)(img + (size_t)(b0 + r0) * DD);
        const float4* xp1 = (const float4*)(img + (size_t)(b0 + r1) * DD);
        const float4* wp  = (const float4*)(l1w + (size_t)c * DD);
        float a0 = 0.f, b0v = 0.f, a1 = 0.f, b1v = 0.f;
        #pragma unroll 4
        for (int k = 0; k < DD/4; k += 2) {
            float4 w0 = wp[k],  w1 = wp[k+1];
            float4 u0 = xp0[k], u1 = xp0[k+1];
            float4 v0 = xp1[k], v1 = xp1[k+1];
            a0  += w0.x*u0.x + w0.y*u0.y + w0.z*u0.z + w0.w*u0.w;
            b0v += w1.x*u1.x + w1.y*u1.y + w1.z*u1.z + w1.w*u1.w;
            a1  += w0.x*v0.x + w0.y*v0.y + w0.z*v0.z + w0.w*v0.w;
            b1v += w1.x*v1.x + w1.y*v1.y + w1.z*v1.z + w1.w*v1.w;
        }
        float h0 = a0 + b0v + l1b[c];
        float h1 = a1 + b1v + l1b[c];
        xs[r0][c] = (h0 >= 0.f) ? h0 : 0.01f*h0;
        xs[r1][c] = (h1 >= 0.f) ? h1 : 0.01f*h1;
    }
    __syncthreads();

    const int wav  = tid >> 6;
    const int lane = tid & 63;
    int  len   = TT;
    bool found = false;
    int  tex   = TT;

    for (int t = 0; t < TT; ++t) {
        if (tid == 0) sh_stable = 1;

        // ---------- gates GEMM: k-outer / m-inner, unconditional ----------
        if (t == 0) {
            // h_prev = 0: r/z/i_n from w_ih only; h_n column = b_hh_n (bias only)
            float acc[NB];
            #pragma unroll
            for (int m = 0; m < NB; ++m) acc[m] = bj;
            if (tid < 384) {
                const float4* wp = (const float4*)(wih + (size_t)tid * HH);
                #pragma unroll
                for (int k = 0; k < HH/4; ++k) {
                    float4 w = wp[k];
                    #pragma unroll
                    for (int m = 0; m < NB; ++m) {
                        float4 x = *(const float4*)&xs[m][4*k];
                        acc[m] += w.x*x.x + w.y*x.y + w.z*x.z + w.w*x.w;
                    }
                }
            }
            #pragma unroll
            for (int m = 0; m < NB; ++m) gs[m][tid] = acc[m];
        } else {
            float acc[NB];
            #pragma unroll
            for (int m = 0; m < NB; ++m) acc[m] = bj;
            const float4* wv = (const float4*)wreg;
            #pragma unroll
            for (int k = 0; k < HH/4; ++k) {
                float4 w = wv[k];       // one AGPR->VGPR fetch, used for 8 rows
                #pragma unroll
                for (int m = 0; m < NB; ++m) {
                    float4 x = *(const float4*)&xs[m][4*k];
                    acc[m] += w.x*x.x + w.y*x.y + w.z*x.z + w.w*x.w;
                }
            }
            #pragma unroll
            for (int m = 0; m < NB; ++m) gs[m][tid] = acc[m];
        }
        __syncthreads();   // A

        // ---------- gate nonlinearity + state update (+ fixed-point compare) ----------
        {
            const int i  = tid & 127;
            const int mh = tid >> 7;
            bool changed = false;
            #pragma unroll
            for (int g = 0; g < 2; ++g) {
                const int m = mh + 4*g;
                float r  = sigm(gs[m][i]);
                float z  = sigm(gs[m][HH + i]);
                float n  = tanhf(gs[m][2*HH + i] + r * gs[m][3*HH + i]);
                float hp = (t == 0) ? 0.f : xs[m][i];
                float h  = (1.f - z) * n + z * hp;
                changed |= (__float_as_uint(h) != __float_as_uint(hp));
                xs[m][i] = h;
                xl[m][i] = (h >= 0.f) ? h : 0.01f * h;
            }
            if (changed) sh_stable = 0;   // benign multi-writer race
        }
        __syncthreads();   // B

        // bitwise fixed point: all future chars identical to chs contents.
        if (t > 0 && sh_stable) { tex = t; break; }

        // ---------- chars = leaky(h) @ l2w.T + l2b from LDS l2t (384 thr, 2 rows) ----
        if (tid < 384) {
            const int m0 = 2 * g3, m1 = m0 + 1;
            float a0 = cbias, a1 = cbias;
            #pragma unroll
            for (int k4 = 0; k4 < HH/4; ++k4) {
                float4 w  = *(const float4*)&l2t[k4][c3][0];
                float4 x0 = *(const float4*)&xl[m0][4*k4];
                float4 x1 = *(const float4*)&xl[m1][4*k4];
                a0 += w.x*x0.x + w.y*x0.y + w.z*x0.z + w.w*x0.w;
                a1 += w.x*x1.x + w.y*x1.y + w.z*x1.z + w.w*x1.w;
            }
            chs[m0][c3] = a0;
            chs[m1][c3] = a1;
        }
        __syncthreads();   // C

        // ---------- max / divide / threshold / sparse scatter / lens ----------
        {
            float v0 = chs[wav][lane];
            float v1 = (lane < 32) ? chs[wav][64 + lane] : -INFINITY;
            float mx = fmaxf(v0, v1);
            #pragma unroll
            for (int s = 32; s > 0; s >>= 1) mx = fmaxf(mx, __shfl_xor(mx, s, 64));
            float q0 = v0 / mx;
            size_t base = ((size_t)(b0 + wav) * TT + t) * CC;
            if (q0 > THRV) out[base + lane] = q0;
            if (lane < 32) {
                float q1 = v1 / mx;
                if (q1 > THRV) out[base + 64 + lane] = q1;
            }
            float q52 = __shfl(q0, 52, 64);
            if (!found && q52 == 1.0f) { found = true; len = t + 1; }
        }
        // no trailing barrier: barriers A,B of next iter separate these chs reads
        // from the next chars-phase writes.
    }

    // ---- epilogue: replicate stable chars for t in [tex, TT) ----
    if (tex < TT) {
        float v0 = chs[wav][lane];
        float v1 = (lane < 32) ? chs[wav][64 + lane] : -INFINITY;
        float mx = fmaxf(v0, v1);
        #pragma unroll
        for (int s = 32; s > 0; s >>= 1) mx = fmaxf(mx, __shfl_xor(mx, s, 64));
        size_t rowbase = (size_t)(b0 + wav) * TT * CC;
        float q0 = v0 / mx;
        if (q0 > THRV)
            for (int t = tex; t < TT; ++t) out[rowbase + (size_t)t * CC + lane] = q0;
        if (lane < 32) {
            float q1 = v1 / mx;
            if (q1 > THRV)
                for (int t = tex; t < TT; ++t) out[rowbase + (size_t)t * CC + 64 + lane] = q1;
        }
        // lens: chars at every t >= tex-1 are identical, so any char-52 argmax
        // was already recorded. len is final.
    }

    if (lane == 0) lens[b0 + wav] = (float)len;
}

extern "C" void kernel_launch(void* const* d_in, const int* in_sizes, int n_in,
                              void* d_out, int out_size, void* d_ws, size_t ws_size,
                              hipStream_t stream)
{
    const float* img = (const float*)d_in[0];
    const float* l1w = (const float*)d_in[1];
    const float* l1b = (const float*)d_in[2];
    const float* wih = (const float*)d_in[3];
    const float* whh = (const float*)d_in[4];
    const float* bih = (const float*)d_in[5];
    const float* bhh = (const float*)d_in[6];
    const float* l2w = (const float*)d_in[7];
    const float* l2b = (const float*)d_in[8];

    float* out  = (float*)d_out;
    float* lens = out + (size_t)2048 * TT * CC;

    // titles is ~99% zeros: clear everything, kernel scatters only survivors.
    hipMemsetAsync(d_out, 0, (size_t)out_size * sizeof(float), stream);

    gru_title<<<dim3(2048 / NB), dim3(512), 0, stream>>>(
        img, l1w, l1b, wih, whh, bih, bhh, l2w, l2b, out, lens);
}